// Round 7
// baseline (7680.830 us; speedup 1.0000x reference)
//
#include <hip/hip_runtime.h>
#include <math.h>

#define VOCAB 20000
#define EDIM  100
#define HDIM  200
#define KTAG  17
#define BATCH 128
#define TLEN  512

// ws layout (float offsets)
static const size_t PROJ_OFF = 0;              // 2 * 20000 * 800 = 32,000,000 floats
static const size_t LSTM_OFF = 32102464;       // 512*128*400 = 26,214,400
static const size_t EM_OFF   = 58316864;       // 512*128*17 = 1,114,112
// W2 (packed Whh, 80,000 float4 = 320,000 floats) overlaps the EM region:
// written by k0, read by k2, dead once k3 overwrites em.
// total = 59,430,976 floats = 237,723,904 bytes

// ---------------- K0: pack Whh into stream-friendly layout ----------------
// W2f4[d][k4][e][g] = Whh_d[row = g*200+e][k = 4*k4 .. 4*k4+3], k4 in [0,50)
// k2's thread (kh,te) reads 4 contiguous float4 (g=0..3) per k4 group; lanes
// (consecutive te) are 64B apart -> coalesced streaming, L2-resident (1.28 MB).
__global__ __launch_bounds__(256) void k0_pack(const float* __restrict__ Whh_f,
                                               const float* __restrict__ Whh_b,
                                               float* __restrict__ ws)
{
    int i = blockIdx.x * 256 + threadIdx.x;
    if (i >= 80000) return;
    int d = i / 40000, r = i % 40000;
    int k4 = r / 800, r2 = r % 800;
    int e = r2 >> 2, g = r2 & 3;
    const float* W = d ? Whh_b : Whh_f;
    float4 v = *(const float4*)(W + (size_t)(g * 200 + e) * 200 + 4 * k4);
    ((float4*)(ws + EM_OFF))[i] = v;
}

// ---------------- K1: per-vocab input projections ----------------
__global__ __launch_bounds__(256) void k1_proj(const float* __restrict__ emb,
                                               const float* __restrict__ Wf,
                                               const float* __restrict__ Wb,
                                               float* __restrict__ ws)
{
    int blk = blockIdx.x;
    int d = blk / 313, vt = blk % 313;
    const float* Wih = d ? Wb : Wf;
    float* proj = ws + PROJ_OFF + (size_t)d * VOCAB * 800;
    __shared__ float elds[64][104];
    __shared__ float olds[64][4][26];
    int tid = threadIdx.x;
    for (int idx = tid; idx < 64 * EDIM; idx += 256) {
        int r = idx / EDIM, c = idx % EDIM;
        int v = vt * 64 + r;
        elds[r][c] = (v < VOCAB) ? emb[(size_t)v * EDIM + c] : 0.f;
    }
    __syncthreads();
    int lane = tid & 63, wq = tid >> 6;
    float4 er[25];
#pragma unroll
    for (int i = 0; i < 25; i++) er[i] = *(const float4*)&elds[lane][4 * i];
#pragma unroll 1
    for (int round = 0; round < 8; round++) {
#pragma unroll 1
        for (int m = 0; m < 25; m++) {
            int oj = wq * 200 + round * 25 + m;      // wave-uniform
            int e = oj >> 2, g = oj & 3;
            int row = __builtin_amdgcn_readfirstlane(g * HDIM + e);
            const float* wrow = Wih + (size_t)row * EDIM;
            float acc = 0.f;
#pragma unroll
            for (int i = 0; i < 25; i++) {
                float4 w4 = *(const float4*)&wrow[4 * i];
                acc += w4.x * er[i].x + w4.y * er[i].y + w4.z * er[i].z + w4.w * er[i].w;
            }
            olds[lane][wq][m] = acc;
        }
        __syncthreads();
        for (int idx = tid; idx < 6400; idx += 256) {
            int vloc = idx / 100, rem = idx % 100;
            int q = rem / 25, c = rem % 25;
            int vv = vt * 64 + vloc;
            if (vv < VOCAB) proj[(size_t)vv * 800 + q * 200 + round * 25 + c] = olds[vloc][q][c];
        }
        __syncthreads();
    }
}

// ---------------- K2: bidirectional LSTM, zero cross-wg communication ----------------
// R6 tuning: 128 wgs (dir x 64 batch-pairs) -> 128 CUs; 4-deep register pipeline
// on the W stream (issue distance ~200cyc >= L2 latency). Per thread (kh,te):
// 4 gate rows of elem te, k-half kh, 2 batches. 800 FMA + 100 W-float4 + 50 ds.
__global__ __launch_bounds__(512, 2) void k2_lstm(const int* __restrict__ sentence,
                                                  const float* __restrict__ bf,
                                                  const float* __restrict__ bb,
                                                  float* __restrict__ ws)
{
    int w = blockIdx.x;               // 128 = 2 dirs x 64 batch-pair tiles
    int d = w >> 6, bt = w & 63;
    int B0 = bt * 2;
    const float* bvec = d ? bb : bf;
    const float* proj = ws + PROJ_OFF + (size_t)d * VOCAB * 800;
    const float4* W2 = (const float4*)(ws + EM_OFF) + (size_t)d * 40000;
    float* lstm_out = ws + LSTM_OFF;

    __shared__ float h_lds[2][2][208];
    __shared__ float red[8][204];     // kh1 partials: [batch*4+gate][te], conflict-free
    __shared__ int   tok[2][TLEN];

    int tid = threadIdx.x;
    int kh = tid >> 8, te = tid & 255;
    bool active = te < 200;

    // preload tokens for this wg's 2 batches (coalesced, once)
#pragma unroll
    for (int b = 0; b < 2; b++)
        tok[b][tid] = sentence[(size_t)(B0 + b) * TLEN + tid];
    for (int i = tid; i < 2 * 208; i += 512) ((float*)h_lds[0])[i] = 0.f;

    float bias_i = 0.f, bias_f = 0.f, bias_g = 0.f, bias_o = 0.f;
    if (kh == 0 && active) {
        bias_i = bvec[te];
        bias_f = bvec[200 + te];
        bias_g = bvec[400 + te];
        bias_o = bvec[600 + te];
    }
    const float4* wbase = W2 + ((size_t)(kh * 25) * 200 + (active ? te : 0)) * 4;
    float c0 = 0.f, c1 = 0.f;
    __syncthreads();

#pragma unroll 1
    for (int t = 0; t < TLEN; t++) {
        int t_eff = d ? (TLEN - 1 - t) : t;
        int p = t & 1;

        // xp gathers: issued at step top, consumed in the epilogue (hidden under FMA)
        float4 xp0, xp1;
        if (kh == 0 && active) {
            xp0 = *(const float4*)(proj + (size_t)tok[0][t_eff] * 800 + 4 * te);
            xp1 = *(const float4*)(proj + (size_t)tok[1][t_eff] * 800 + 4 * te);
        }

        float aI0 = 0.f, aF0 = 0.f, aG0 = 0.f, aO0 = 0.f;
        float aI1 = 0.f, aF1 = 0.f, aG1 = 0.f, aO1 = 0.f;

        if (active) {
            const float* hp0 = &h_lds[p][0][kh * 100];
            const float* hp1 = &h_lds[p][1][kh * 100];
            // 4-deep rotating register pipeline over 25 k4-groups
            float4 wv[4][4];
            float4 hv0[4], hv1[4];
#pragma unroll
            for (int s = 0; s < 4; s++) {
                const float4* wp = wbase + (size_t)s * 800;
                wv[s][0] = wp[0]; wv[s][1] = wp[1]; wv[s][2] = wp[2]; wv[s][3] = wp[3];
                hv0[s] = *(const float4*)(hp0 + 4 * s);
                hv1[s] = *(const float4*)(hp1 + 4 * s);
            }
#pragma unroll
            for (int j = 0; j < 25; j++) {
                const int s = j & 3;
                // consume group j
                {
                    float4 W0 = wv[s][0], W1 = wv[s][1], W2r = wv[s][2], W3 = wv[s][3];
                    float4 H0 = hv0[s], H1 = hv1[s];
                    aI0 += W0.x * H0.x + W0.y * H0.y + W0.z * H0.z + W0.w * H0.w;
                    aF0 += W1.x * H0.x + W1.y * H0.y + W1.z * H0.z + W1.w * H0.w;
                    aG0 += W2r.x * H0.x + W2r.y * H0.y + W2r.z * H0.z + W2r.w * H0.w;
                    aO0 += W3.x * H0.x + W3.y * H0.y + W3.z * H0.z + W3.w * H0.w;
                    aI1 += W0.x * H1.x + W0.y * H1.y + W0.z * H1.z + W0.w * H1.w;
                    aF1 += W1.x * H1.x + W1.y * H1.y + W1.z * H1.z + W1.w * H1.w;
                    aG1 += W2r.x * H1.x + W2r.y * H1.y + W2r.z * H1.z + W2r.w * H1.w;
                    aO1 += W3.x * H1.x + W3.y * H1.y + W3.z * H1.z + W3.w * H1.w;
                }
                // prefetch group j+4 into slot s
                if (j + 4 < 25) {
                    const float4* wp = wbase + (size_t)(j + 4) * 800;
                    wv[s][0] = wp[0]; wv[s][1] = wp[1]; wv[s][2] = wp[2]; wv[s][3] = wp[3];
                    hv0[s] = *(const float4*)(hp0 + 4 * (j + 4));
                    hv1[s] = *(const float4*)(hp1 + 4 * (j + 4));
                }
            }
        }

        // kh=1 contributes its k-half via LDS
        if (kh == 1 && active) {
            red[0][te] = aI0; red[1][te] = aF0; red[2][te] = aG0; red[3][te] = aO0;
            red[4][te] = aI1; red[5][te] = aF1; red[6][te] = aG1; red[7][te] = aO1;
        }
        __syncthreads();

        if (kh == 0 && active) {
            int pn = p ^ 1;
            float gi, gf, gg, go, sI, sF, sO, hv;
            // batch 0
            gi = aI0 + red[0][te] + xp0.x + bias_i;
            gf = aF0 + red[1][te] + xp0.y + bias_f;
            gg = aG0 + red[2][te] + xp0.z + bias_g;
            go = aO0 + red[3][te] + xp0.w + bias_o;
            sI = 1.f / (1.f + expf(-gi)); sF = 1.f / (1.f + expf(-gf)); sO = 1.f / (1.f + expf(-go));
            c0 = sF * c0 + sI * tanhf(gg);
            hv = sO * tanhf(c0);
            h_lds[pn][0][te] = hv;
            lstm_out[((size_t)t_eff * BATCH + B0 + 0) * 400 + d * 200 + te] = hv;
            // batch 1
            gi = aI1 + red[4][te] + xp1.x + bias_i;
            gf = aF1 + red[5][te] + xp1.y + bias_f;
            gg = aG1 + red[6][te] + xp1.z + bias_g;
            go = aO1 + red[7][te] + xp1.w + bias_o;
            sI = 1.f / (1.f + expf(-gi)); sF = 1.f / (1.f + expf(-gf)); sO = 1.f / (1.f + expf(-go));
            c1 = sF * c1 + sI * tanhf(gg);
            hv = sO * tanhf(c1);
            h_lds[pn][1][te] = hv;
            lstm_out[((size_t)t_eff * BATCH + B0 + 1) * 400 + d * 200 + te] = hv;
        }
        __syncthreads();
    }
}

// ---------------- K3: emissions em = lstm_out @ W_fc^T + b_fc ----------------
__global__ __launch_bounds__(256) void k3_em(const float* __restrict__ Wfc,
                                             const float* __restrict__ bfc,
                                             float* __restrict__ ws)
{
    __shared__ float llds[15][404];
    __shared__ float wlds[17][404];
    const float* lstm = ws + LSTM_OFF;
    float* em = ws + EM_OFF;
    int n0 = blockIdx.x * 15;
    int tid = threadIdx.x;
    for (int idx = tid; idx < 15 * 400; idx += 256) {
        int r = idx / 400, c = idx % 400;
        int n = n0 + r;
        llds[r][c] = (n < BATCH * TLEN) ? lstm[(size_t)n * 400 + c] : 0.f;
    }
    for (int idx = tid; idx < 17 * 400; idx += 256) {
        int r = idx / 400, c = idx % 400;
        wlds[r][c] = Wfc[r * 400 + c];
    }
    __syncthreads();
    if (tid < 255) {
        int tk = tid / 17, k = tid % 17;
        int n = n0 + tk;
        if (n < BATCH * TLEN) {
            float acc = 0.f;
#pragma unroll
            for (int i = 0; i < 100; i++) {
                float4 a  = *(const float4*)&llds[tk][4 * i];
                float4 wv = *(const float4*)&wlds[k][4 * i];
                acc += a.x * wv.x + a.y * wv.y + a.z * wv.z + a.w * wv.w;
            }
            em[(size_t)n * KTAG + k] = acc + bfc[k];
        }
    }
}

// ---------------- K4: bin_scores = mean_t(lstm_out) @ W_bin^T + b_bin ----------------
__global__ __launch_bounds__(256) void k4_bin(const float* __restrict__ Wbin,
                                              const float* __restrict__ bbin,
                                              float* __restrict__ ws,
                                              float* __restrict__ out)
{
    int b = blockIdx.x, tid = threadIdx.x;
    const float* lstm = ws + LSTM_OFF;
    __shared__ float m_lds[400];
    float a0 = 0.f, a1 = 0.f;
#pragma unroll 4
    for (int t = 0; t < TLEN; t++) {
        const float* rowp = lstm + ((size_t)t * BATCH + b) * 400;
        a0 += rowp[tid];
        if (tid < 144) a1 += rowp[256 + tid];
    }
    m_lds[tid] = a0 * (1.f / 512.f);
    if (tid < 144) m_lds[256 + tid] = a1 * (1.f / 512.f);
    __syncthreads();
    int wv = tid >> 6, lane = tid & 63;
    if (wv < 2) {
        float p = 0.f;
        for (int j = lane; j < 400; j += 64) p += m_lds[j] * Wbin[wv * 400 + j];
#pragma unroll
        for (int off = 32; off > 0; off >>= 1) p += __shfl_down(p, off);
        if (lane == 0) out[(size_t)BATCH * TLEN + b * 2 + wv] = p + bbin[wv];
    }
}

// ---------------- K5: masked Viterbi decode + traceback ----------------
__global__ __launch_bounds__(64) void k5_vit(const int* __restrict__ masks,
                                             const float* __restrict__ trans,
                                             const float* __restrict__ startv,
                                             const float* __restrict__ endv,
                                             const float* __restrict__ ws,
                                             float* __restrict__ out)
{
    int b = blockIdx.x, lane = threadIdx.x;
    const float* em = ws + EM_OFF;
    __shared__ float emlds[TLEN * KTAG];
    __shared__ unsigned char bpl[TLEN * KTAG];
    __shared__ int mlds[TLEN];
    __shared__ unsigned char tagl[TLEN];
    __shared__ float slds[KTAG];
    __shared__ float fin[KTAG];

    for (int idx = lane; idx < TLEN * KTAG; idx += 64) {
        int tt = idx / KTAG, j = idx - tt * KTAG;
        emlds[idx] = em[((size_t)tt * BATCH + b) * KTAG + j];
    }
    for (int idx = lane; idx < TLEN; idx += 64) mlds[idx] = masks[(size_t)b * TLEN + idx];
    bool on = lane < KTAG;
    float tr[KTAG];
    if (on) {
#pragma unroll
        for (int i = 0; i < KTAG; i++) tr[i] = trans[i * KTAG + lane];
    }
    __syncthreads();
    float sown = 0.f;
    if (on) { sown = startv[lane] + emlds[lane]; slds[lane] = sown; }
    __syncthreads();
#pragma unroll 1
    for (int t = 1; t < TLEN; t++) {
        int m = mlds[t];
        float ns = sown; int idx = lane;
        if (on) {
            float best = -3.4e38f; int bi = 0;
#pragma unroll
            for (int i = 0; i < KTAG; i++) {
                float vv = slds[i] + tr[i];
                if (vv > best) { best = vv; bi = i; }   // strict > => first max (matches jnp.argmax)
            }
            if (m != 0) { ns = best + emlds[t * KTAG + lane]; idx = bi; }
        }
        __syncthreads();
        if (on) { sown = ns; slds[lane] = ns; bpl[t * KTAG + lane] = (unsigned char)idx; }
        __syncthreads();
    }
    if (on) fin[lane] = sown + endv[lane];
    __syncthreads();
    if (lane == 0) {
        float bb = -3.4e38f; int bi = 0;
#pragma unroll
        for (int i = 0; i < KTAG; i++) if (fin[i] > bb) { bb = fin[i]; bi = i; }
        int cur = bi;
        tagl[TLEN - 1] = (unsigned char)cur;
        for (int t = TLEN - 1; t >= 1; t--) {
            cur = bpl[t * KTAG + cur];
            tagl[t - 1] = (unsigned char)cur;
        }
    }
    __syncthreads();
    for (int s = lane; s < TLEN; s += 64) out[(size_t)b * TLEN + s] = (float)tagl[s];
}

extern "C" void kernel_launch(void* const* d_in, const int* in_sizes, int n_in,
                              void* d_out, int out_size, void* d_ws, size_t ws_size,
                              hipStream_t stream)
{
    (void)in_sizes; (void)n_in; (void)out_size; (void)ws_size;
    const int*   sentence = (const int*)d_in[0];
    const int*   masks    = (const int*)d_in[1];
    const float* emb      = (const float*)d_in[2];
    const float* Wih_f    = (const float*)d_in[3];
    const float* Whh_f    = (const float*)d_in[4];
    const float* b_f      = (const float*)d_in[5];
    const float* Wih_b    = (const float*)d_in[6];
    const float* Whh_b    = (const float*)d_in[7];
    const float* b_b      = (const float*)d_in[8];
    const float* W_fc     = (const float*)d_in[9];
    const float* b_fc     = (const float*)d_in[10];
    const float* W_bin    = (const float*)d_in[11];
    const float* b_bin    = (const float*)d_in[12];
    const float* trans    = (const float*)d_in[13];
    const float* startv   = (const float*)d_in[14];
    const float* endv     = (const float*)d_in[15];
    float* ws  = (float*)d_ws;
    float* out = (float*)d_out;

    k0_pack<<<313, 256, 0, stream>>>(Whh_f, Whh_b, ws);
    k1_proj<<<626, 256, 0, stream>>>(emb, Wih_f, Wih_b, ws);
    k2_lstm<<<128, 512, 0, stream>>>(sentence, b_f, b_b, ws);
    k3_em<<<4370, 256, 0, stream>>>(W_fc, b_fc, ws);
    k4_bin<<<128, 256, 0, stream>>>(W_bin, b_bin, ws, out);
    k5_vit<<<128, 64, 0, stream>>>(masks, trans, startv, endv, ws, out);
}